// Round 2
// baseline (239.851 us; speedup 1.0000x reference)
//
#include <hip/hip_runtime.h>
#include <hip/hip_bf16.h>
#include <cstdint>
#include <cstddef>

using bf16 = __hip_bfloat16;
typedef __attribute__((ext_vector_type(8))) short short8;
typedef __attribute__((ext_vector_type(4))) float floatx4;

#define B_ 4
#define T_ 2048
#define C_ 1024
#define H_ 16
#define HS_ 64
#define BT_ (B_*T_)
#define N3C (3*C_)

#define MFMA16(a,b,c) __builtin_amdgcn_mfma_f32_16x16x32_bf16((a),(b),(c),0,0,0)

#if __has_builtin(__builtin_amdgcn_exp2f)
#define EXP2(x) __builtin_amdgcn_exp2f(x)
#else
#define EXP2(x) exp2f(x)
#endif

static __device__ __forceinline__ void gld16(const bf16* g, bf16* l) {
  __builtin_amdgcn_global_load_lds(
      (const __attribute__((address_space(1))) unsigned int*)g,
      (__attribute__((address_space(3))) unsigned int*)l, 16, 0, 0);
}

static __device__ __forceinline__ unsigned short f2bf_us(float x) {
  bf16 b = __float2bfloat16(x);
  return *(unsigned short*)&b;
}

// ---------------- fused prep: cast x + transpose-cast both weights ----------
__global__ __launch_bounds__(256)
void k_prep(const float* __restrict__ x, bf16* __restrict__ xb,
            const float* __restrict__ Wqkv, bf16* __restrict__ wqkvT,
            const float* __restrict__ Wproj, bf16* __restrict__ wprojT)
{
  const int bid = blockIdx.x, tid = threadIdx.x;
  __shared__ float tile[64][65];

  if (bid < 4096) {
    const int i = bid*256 + tid;
    const float4 v0 = ((const float4*)x)[2*i];
    const float4 v1 = ((const float4*)x)[2*i + 1];
    union { bf16 b[8]; uint4 u; } cvt;
    cvt.b[0] = __float2bfloat16(v0.x);
    cvt.b[1] = __float2bfloat16(v0.y);
    cvt.b[2] = __float2bfloat16(v0.z);
    cvt.b[3] = __float2bfloat16(v0.w);
    cvt.b[4] = __float2bfloat16(v1.x);
    cvt.b[5] = __float2bfloat16(v1.y);
    cvt.b[6] = __float2bfloat16(v1.z);
    cvt.b[7] = __float2bfloat16(v1.w);
    ((uint4*)xb)[i] = cvt.u;
    return;
  }

  const float* in; bf16* out; int N, n0, k0;
  if (bid < 4864) {
    const int j = bid - 4096;
    in = Wqkv; out = wqkvT; N = N3C;
    n0 = (j % 48) * 64; k0 = (j / 48) * 64;
  } else {
    const int j = bid - 4864;
    in = Wproj; out = wprojT; N = C_;
    n0 = (j % 16) * 64; k0 = (j / 16) * 64;
  }
  const int r = tid >> 6, c = tid & 63;
  #pragma unroll
  for (int j = 0; j < 16; ++j)
    tile[r + j*4][c] = in[(size_t)(k0 + r + j*4) * N + n0 + c];
  __syncthreads();
  #pragma unroll
  for (int j = 0; j < 16; ++j) {
    int rr = r + j*4;
    out[(size_t)(n0 + rr) * C_ + k0 + c] = __float2bfloat16(tile[c][rr]);
  }
}

// ---------------- 256x256 deep-pipelined QKV GEMM (counted vmcnt) -----------
// R11: port of the 8-phase/counted-vmcnt template under 64KB LDS:
//  - tile 256x256, BK=32, dbuf (2x16KB A + 2x16KB B = 64KB), 8 waves 2Mx4N,
//    acc[8][4], 64 MFMA per K-tile per wave-pair phase split 16+16.
//  - staging: 4 gld16 per K-tile issued one tile ahead; the barrier never
//    drains them: s_waitcnt vmcnt(4) keeps the next tile's loads in flight
//    across raw s_barrier (T3+T4). setprio(1) around MFMA clusters (T5).
//  - LDS rows 32 bf16 (64B), chunk c of row r at physical c^(r&3): staging
//    lane-linear (gld16-compatible), frag reads spread 8 lanes/4-bank group
//    (b128 minimum aliasing, conflict-free).
//  - hazards: RAW = vmcnt(4)+B1 before first ds_read of tile i (its loads
//    were issued at tile i-1's phase 0, 2 phases earlier). WAR = end-of-tile
//    B2: all frag reads retire (lgkm) before the MFMAs preceding B2; next
//    tile's glds (other buffer) issue only after B2.
// Epilogue: nb<4 -> Q (pre-scaled), 4-7 -> K, 8-11 -> V transpose via 4
// LDS passes of 64 cols into key-permuted Vt [B,H,HS,T].
__global__ __launch_bounds__(512, 1)
void k_gemm256(const bf16* __restrict__ A, const bf16* __restrict__ Bt,
               bf16* __restrict__ Qb, bf16* __restrict__ Kb, bf16* __restrict__ Vt)
{
  __shared__ __align__(16) char smem[65536];
  bf16* const sA = (bf16*)smem;               // [2][8192] : 256 rows x 32
  bf16* const sB = (bf16*)(smem + 32768);     // [2][8192]

  const int tid  = threadIdx.x;
  const int lane = tid & 63, wave = tid >> 6;
  const int quad = lane >> 4, l16 = lane & 15;
  const int wm = wave >> 2, wn = wave & 3;

  const int g = blockIdx.x;                   // 384 blocks
  const int xcd = g & 7;
  const int local = g >> 3;                   // 0..47
  const int nb = local % 12;
  const int mb = (local / 12) * 8 + xcd;      // 0..31
  const int m0 = mb * 256, n0 = nb * 256;

  // staging: thread t -> row t>>2 (+128 for 2nd round), phys chunk t&3,
  // global chunk (t&3)^(row&3); LDS dest = tid*16 bytes (lane-linear).
  const int ra = tid >> 2;
  const int gc = (tid & 3) ^ (ra & 3);
  const bf16* aptr = A  + (size_t)(m0 + ra) * C_ + gc*8;
  const bf16* bptr = Bt + (size_t)(n0 + ra) * C_ + gc*8;

  floatx4 acc[8][4] = {};
  const int aoff = (wm*128 + l16)*32 + (quad ^ (l16 & 3))*8;
  const int boff = (wn*64  + l16)*32 + (quad ^ (l16 & 3))*8;

  // prologue: stage K-tile 0 into buf 0
  gld16(aptr,            sA + tid*8);
  gld16(aptr + 128*C_,   sA + 4096 + tid*8);
  gld16(bptr,            sB + tid*8);
  gld16(bptr + 128*C_,   sB + 4096 + tid*8);

  for (int i = 0; i < 32; ++i) {
    const int cur = i & 1;
    if (i + 1 < 32) {
      const int k0 = (i + 1) * 32;
      bf16* sa = sA + (cur ^ 1) * 8192;
      bf16* sb = sB + (cur ^ 1) * 8192;
      gld16(aptr + k0,           sa + tid*8);
      gld16(aptr + 128*C_ + k0,  sa + 4096 + tid*8);
      gld16(bptr + k0,           sb + tid*8);
      gld16(bptr + 128*C_ + k0,  sb + 4096 + tid*8);
      asm volatile("s_waitcnt vmcnt(4)" ::: "memory");   // tile i complete; i+1 in flight
    } else {
      asm volatile("s_waitcnt vmcnt(0)" ::: "memory");
    }
    asm volatile("s_barrier" ::: "memory");              // B1
    const bf16* sa = sA + cur * 8192;
    const bf16* sb = sB + cur * 8192;
    short8 a0[4], bq[4], a1[4];
    #pragma unroll
    for (int ii = 0; ii < 4; ++ii) a0[ii] = *(const short8*)&sa[aoff + ii*512];
    #pragma unroll
    for (int j = 0; j < 4; ++j)   bq[j]  = *(const short8*)&sb[boff + j*512];
    __builtin_amdgcn_s_setprio(1);
    #pragma unroll
    for (int ii = 0; ii < 4; ++ii)
      #pragma unroll
      for (int j = 0; j < 4; ++j)
        acc[ii][j] = MFMA16(a0[ii], bq[j], acc[ii][j]);
    __builtin_amdgcn_s_setprio(0);
    #pragma unroll
    for (int ii = 0; ii < 4; ++ii) a1[ii] = *(const short8*)&sa[aoff + 2048 + ii*512];
    asm volatile("s_barrier" ::: "memory");              // B_mid (lockstep)
    __builtin_amdgcn_s_setprio(1);
    #pragma unroll
    for (int ii = 0; ii < 4; ++ii)
      #pragma unroll
      for (int j = 0; j < 4; ++j)
        acc[4+ii][j] = MFMA16(a1[ii], bq[j], acc[4+ii][j]);
    __builtin_amdgcn_s_setprio(0);
    asm volatile("s_barrier" ::: "memory");              // B2 (reads retired)
  }

  if (nb >= 8) {
    // ---- V: 4 LDS passes of 64 cols -> key-permuted Vt [B,H,HS,T] ----
    unsigned short* epi = (unsigned short*)smem;   // [64 cc][264 tl-pad]
    const int b  = m0 >> 11;
    const int t0 = m0 & 2047;
    #pragma unroll 1
    for (int pass = 0; pass < 4; ++pass) {
      if (wn == pass) {
        #pragma unroll
        for (int ii = 0; ii < 8; ++ii) {
          const int tl = wm*128 + ii*16 + quad*4;
          #pragma unroll
          for (int j = 0; j < 4; ++j) {
            const int ccl = j*16 + l16;
            #pragma unroll
            for (int r = 0; r < 4; ++r)
              epi[ccl*264 + tl + r] = f2bf_us(acc[ii][j][r]);
          }
        }
      }
      __syncthreads();
      const int h = ((n0 - 2*C_) >> 6) + pass;
      #pragma unroll
      for (int it = 0; it < 16; ++it) {
        const int id = it*512 + tid;        // 0..8191 dword-pairs
        const int tp = id & 31;
        const int rest = id >> 5;           // 0..255
        const int tl64 = (rest & 3) * 64;
        const int ccl = rest >> 2;          // 0..63  (= d)
        const int k0p = tp + (tp & 16);     // keys (k0p,k0p+16) -> pos (2tp,2tp+1)
        const unsigned lo = epi[ccl*264 + tl64 + k0p];
        const unsigned hi = epi[ccl*264 + tl64 + k0p + 16];
        unsigned* row = (unsigned*)(Vt + ((size_t)(b*H_ + h) * HS_ + ccl) * T_);
        row[(t0 >> 1) + tl64/2 + tp] = lo | (hi << 16);
      }
      if (pass < 3) __syncthreads();
    }
  } else {
    #pragma unroll
    for (int ii = 0; ii < 8; ++ii) {
      const int rowb = m0 + wm*128 + ii*16 + quad*4;
      #pragma unroll
      for (int j = 0; j < 4; ++j) {
        const int col = n0 + wn*64 + j*16 + l16;
        const int h = (col >> 6) & 15, d = col & 63;
        #pragma unroll
        for (int r = 0; r < 4; ++r) {
          const float v = acc[ii][j][r];
          const int rr = rowb + r;
          const int bb = rr >> 11, t = rr & 2047;
          const size_t addr = (((size_t)(bb*H_ + h) * T_ + t) << 6) + d;
          if (nb < 4) {
            // fold 1/sqrt(64) * log2(e) so attention softmax can use exp2
            Qb[addr] = __float2bfloat16(v * 0.18033688f);
          } else {
            Kb[addr] = __float2bfloat16(v);
          }
        }
      }
    }
  }
}

// ---------------- GEMM: C[M,N] = A[M,K] * Bt[N,K]^T (128^2, proj only) ------
template<int MODE, int NB>
__global__ __launch_bounds__(256, 2)
void k_gemm(const bf16* __restrict__ A, const bf16* __restrict__ Bt,
            int N, int K,
            bf16* __restrict__ Qb, bf16* __restrict__ Kb, bf16* __restrict__ Vt,
            float* __restrict__ Out, const float* __restrict__ bias)
{
  __shared__ __align__(16) char smem[65536];
  bf16* const sAb = (bf16*)smem;               // [2][8192]
  bf16* const sBb = (bf16*)(smem + 32768);     // [2][8192]

  const int tid  = threadIdx.x;
  const int lane = tid & 63, wave = tid >> 6;
  const int quad = lane >> 4, l16 = lane & 15;
  const int wm = wave >> 1, wn = wave & 1;

  const int g = blockIdx.x;
  const int xcd = g & 7;
  const int local = g >> 3;
  const int nb = local % NB;
  const int mb = (local / NB) * 8 + xcd;
  const int m0 = mb * 128, n0 = nb * 128;

  const int ra = tid >> 3;
  const int gc = (tid & 7) ^ (ra & 7);
  const bf16* aptr = A  + (size_t)(m0 + ra) * K + gc*8;
  const bf16* bptr = Bt + (size_t)(n0 + ra) * K + gc*8;
  const size_t rj = (size_t)32 * K;

  floatx4 acc[4][4] = {};
  const int KI = K >> 6;
  const int x7a = l16 & 7;

  for (int i = 0; i <= KI; ++i) {
    __syncthreads();
    if (i < KI) {
      const int k0 = i << 6;
      bf16* sa = sAb + (i & 1) * 8192;
      bf16* sb = sBb + (i & 1) * 8192;
      #pragma unroll
      for (int q2 = 0; q2 < 4; ++q2) {
        gld16(aptr + q2*rj + k0, sa + q2*2048 + tid*8);
        gld16(bptr + q2*rj + k0, sb + q2*2048 + tid*8);
      }
    }
    if (i == 0) continue;
    const bf16* sa = sAb + ((i-1) & 1) * 8192;
    const bf16* sb = sBb + ((i-1) & 1) * 8192;
    #pragma unroll
    for (int ks = 0; ks < 2; ++ks) {
      short8 af[4], bfm[4];
      #pragma unroll
      for (int ii = 0; ii < 4; ++ii)
        af[ii] = *(const short8*)&sa[(wm*64 + ii*16 + l16)*64 + ((ks*4 + quad) ^ x7a)*8];
      #pragma unroll
      for (int ii = 0; ii < 4; ++ii)
        bfm[ii] = *(const short8*)&sb[(wn*64 + ii*16 + l16)*64 + ((ks*4 + quad) ^ x7a)*8];
      #pragma unroll
      for (int ii = 0; ii < 4; ++ii)
        #pragma unroll
        for (int j = 0; j < 4; ++j)
          acc[ii][j] = MFMA16(af[ii], bfm[j], acc[ii][j]);
    }
  }

  #pragma unroll
  for (int i = 0; i < 4; ++i) {
    const int rowb = m0 + wm*64 + i*16 + quad*4;
    #pragma unroll
    for (int j = 0; j < 4; ++j) {
      const int col = n0 + wn*64 + j*16 + l16;
      #pragma unroll
      for (int r = 0; r < 4; ++r) {
        const float v = acc[i][j][r];
        const int rr = rowb + r;
        if (MODE == 1) {
          Out[(size_t)rr * N + col] = v + bias[col];
        }
      }
    }
  }
}

// ---------------- flash attention (causal) ----------------------------------
__global__ __launch_bounds__(256, 3)
void k_attn(const bf16* __restrict__ Q, const bf16* __restrict__ K,
            const bf16* __restrict__ Vt, bf16* __restrict__ att)
{
  __shared__ bf16 kbuf[2][64*64];   // [buf][key][dc^key&7]
  __shared__ bf16 vbuf[2][64*64];   // [buf][d][pc^d&7]  (positions, permuted)
  __shared__ bf16 pbuf[4][32*64];   // per-wave [q][(pc+q)&7 rotation]

  const int tid  = threadIdx.x;
  const int lane = tid & 63, wave = tid >> 6;
  const int quad = lane >> 4, l16 = lane & 15;
  const int x7 = l16 & 7;

  const int g  = blockIdx.x;              // 1024 blocks
  const int bh = (g & 7) * 8 + ((g >> 3) & 7);  // 16 blocks of a bh share XCD g&7
  const int qt = 15 - (g >> 6);           // q-tile index; heavy (qt=15) first
  const int b = bh >> 4, h = bh & 15;

  const bf16* Qp = Q  + (size_t)bh * T_ * HS_;
  const bf16* Kp = K  + (size_t)bh * T_ * HS_;
  const bf16* Vp = Vt + (size_t)bh * HS_ * T_;

  const int qbase = qt*128 + wave*32;
  const int ntk = 2*qt + 2;               // key tiles to process

  short8 qf[2][2];
  #pragma unroll
  for (int mt = 0; mt < 2; ++mt)
    #pragma unroll
    for (int ss = 0; ss < 2; ++ss)
      qf[mt][ss] = *(const short8*)(Qp + (size_t)(qbase + mt*16 + l16) * HS_ + ss*32 + quad*8);

  floatx4 o[2][4] = {};
  float lrow[2][4] = {};

  const bf16* kg[2]; const bf16* vg[2];
  int ldsoff[2];
  #pragma unroll
  for (int it = 0; it < 2; ++it) {
    const int c = it*256 + tid;
    const int row = c >> 3;
    const int col = (c & 7) ^ (row & 7);
    kg[it] = Kp + (size_t)row * HS_ + col*8;
    vg[it] = Vp + (size_t)row * T_ + col*8;
    ldsoff[it] = c*8;
  }

  bf16* pw = pbuf[wave];
  unsigned int* pw32 = (unsigned int*)pw;
  const int c0 = l16 >> 2;
  const int dwl = l16 & 3;

  for (int i = 0; i <= ntk; ++i) {
    __syncthreads();
    if (i < ntk) {
      const int stk0 = i * 64;
      bf16* kb = kbuf[i & 1];
      bf16* vb = vbuf[i & 1];
      #pragma unroll
      for (int it = 0; it < 2; ++it) {
        gld16(kg[it] + (size_t)stk0 * HS_, kb + ldsoff[it]);
        gld16(vg[it] + stk0,               vb + ldsoff[it]);
      }
    }
    if (i == 0) continue;
    const int tk  = i - 1;
    const int tk0 = tk * 64;
    if (tk0 > qbase + 31) continue;
    const bf16* kb = kbuf[tk & 1];
    const bf16* vb = vbuf[tk & 1];

    floatx4 s[2][4] = {};
    __builtin_amdgcn_s_setprio(1);
    #pragma unroll
    for (int nt = 0; nt < 4; ++nt) {
      const int key = nt*16 + l16;
      #pragma unroll
      for (int ss = 0; ss < 2; ++ss) {
        short8 kf = *(const short8*)&kb[(key*8 + ((ss*4+quad) ^ x7))*8];
        s[0][nt] = MFMA16(qf[0][ss], kf, s[0][nt]);
        s[1][nt] = MFMA16(qf[1][ss], kf, s[1][nt]);
      }
    }
    __builtin_amdgcn_s_setprio(0);

    if (tk0 + 63 > qbase) {
      #pragma unroll
      for (int mt = 0; mt < 2; ++mt)
        #pragma unroll
        for (int nt = 0; nt < 4; ++nt) {
          const int key = tk0 + nt*16 + l16;
          #pragma unroll
          for (int r = 0; r < 4; ++r) {
            const int qr = qbase + mt*16 + quad*4 + r;
            if (key > qr) s[mt][nt][r] = -1e30f;
          }
        }
    }

    #pragma unroll
    for (int mt = 0; mt < 2; ++mt) {
      #pragma unroll
      for (int r = 0; r < 4; ++r) {
        const float p0 = EXP2(s[mt][0][r]), p1 = EXP2(s[mt][1][r]);
        const float p2 = EXP2(s[mt][2][r]), p3 = EXP2(s[mt][3][r]);
        lrow[mt][r] += (p0 + p1) + (p2 + p3);
        const int q = mt*16 + quad*4 + r;
        const unsigned w0 = __builtin_amdgcn_perm(__float_as_uint(p1), __float_as_uint(p0), 0x07060302u);
        const unsigned w1 = __builtin_amdgcn_perm(__float_as_uint(p3), __float_as_uint(p2), 0x07060302u);
        pw32[q*32 + (((c0 + q)     & 7) << 2) + dwl] = w0;
        pw32[q*32 + (((c0 + q + 4) & 7) << 2) + dwl] = w1;
      }
    }

    __builtin_amdgcn_s_setprio(1);
    #pragma unroll
    for (int ss = 0; ss < 2; ++ss) {
      short8 pf0 = *(const short8*)&pw[l16*64      + ((4*ss + quad + l16) & 7)*8];
      short8 pf1 = *(const short8*)&pw[(16+l16)*64 + ((4*ss + quad + l16) & 7)*8];
      #pragma unroll
      for (int nd = 0; nd < 4; ++nd) {
        const int d = nd*16 + l16;
        short8 vf = *(const short8*)&vb[(d*8 + ((ss*4+quad) ^ x7))*8];
        o[0][nd] = MFMA16(pf0, vf, o[0][nd]);
        o[1][nd] = MFMA16(pf1, vf, o[1][nd]);
      }
    }
    __builtin_amdgcn_s_setprio(0);
  }

  #pragma unroll
  for (int mt = 0; mt < 2; ++mt) {
    #pragma unroll
    for (int r = 0; r < 4; ++r) {
      float lsum = lrow[mt][r];
      lsum += __shfl_xor(lsum, 1);
      lsum += __shfl_xor(lsum, 2);
      lsum += __shfl_xor(lsum, 4);
      lsum += __shfl_xor(lsum, 8);
      const float inv = 1.0f / lsum;
      const int tt = qbase + mt*16 + quad*4 + r;
      #pragma unroll
      for (int nd = 0; nd < 4; ++nd)
        att[(size_t)(b*T_ + tt) * C_ + h*64 + nd*16 + l16] =
            __float2bfloat16(o[mt][nd][r] * inv);
    }
  }
}

extern "C" void kernel_launch(void* const* d_in, const int* in_sizes, int n_in,
                              void* d_out, int out_size, void* d_ws, size_t ws_size,
                              hipStream_t stream) {
  const float* x     = (const float*)d_in[0];
  const float* Wqkv  = (const float*)d_in[1];
  const float* Wproj = (const float*)d_in[2];
  const float* bproj = (const float*)d_in[3];
  float* out = (float*)d_out;

  char* ws = (char*)d_ws;
  bf16* xb     = (bf16*)(ws + 0);          // 8192x1024       16,777,216 B
  bf16* wqkvT  = (bf16*)(ws + 16777216);   // 3072x1024        6,291,456 B
  bf16* wprojT = (bf16*)(ws + 23068672);   // 1024x1024        2,097,152 B
  bf16* Qb     = (bf16*)(ws + 25165824);   // [B,H,T,HS]      16,777,216 B
  bf16* Kb     = (bf16*)(ws + 41943040);   // [B,H,T,HS]      16,777,216 B
  bf16* Vt     = (bf16*)(ws + 58720256);   // [B,H,HS,T] perm 16,777,216 B
  bf16* att    = (bf16*)(ws + 75497472);   // [B,T,C]         16,777,216 B

  k_prep<<<dim3(5120), 256, 0, stream>>>(x, xb, Wqkv, wqkvT, Wproj, wprojT);
  k_gemm256<<<dim3(384), 512, 0, stream>>>(xb, wqkvT, Qb, Kb, Vt);
  k_attn<<<dim3(1024), 256, 0, stream>>>(Qb, Kb, Vt, att);
  k_gemm<1, 8><<<dim3(512), 256, 0, stream>>>(
      att, wprojT, C_, C_, nullptr, nullptr, nullptr, out, bproj);
}

// Round 3
// 226.748 us; speedup vs baseline: 1.0578x; 1.0578x over previous
//
#include <hip/hip_runtime.h>
#include <hip/hip_bf16.h>
#include <cstdint>
#include <cstddef>

using bf16 = __hip_bfloat16;
typedef __attribute__((ext_vector_type(8))) short short8;
typedef __attribute__((ext_vector_type(4))) float floatx4;

#define B_ 4
#define T_ 2048
#define C_ 1024
#define H_ 16
#define HS_ 64
#define BT_ (B_*T_)
#define N3C (3*C_)

#define MFMA16(a,b,c) __builtin_amdgcn_mfma_f32_16x16x32_bf16((a),(b),(c),0,0,0)

#if __has_builtin(__builtin_amdgcn_exp2f)
#define EXP2(x) __builtin_amdgcn_exp2f(x)
#else
#define EXP2(x) exp2f(x)
#endif

static __device__ __forceinline__ void gld16(const bf16* g, bf16* l) {
  __builtin_amdgcn_global_load_lds(
      (const __attribute__((address_space(1))) unsigned int*)g,
      (__attribute__((address_space(3))) unsigned int*)l, 16, 0, 0);
}

static __device__ __forceinline__ unsigned short f2bf_us(float x) {
  bf16 b = __float2bfloat16(x);
  return *(unsigned short*)&b;
}

// ---------------- fused prep: cast x + transpose-cast both weights ----------
__global__ __launch_bounds__(256)
void k_prep(const float* __restrict__ x, bf16* __restrict__ xb,
            const float* __restrict__ Wqkv, bf16* __restrict__ wqkvT,
            const float* __restrict__ Wproj, bf16* __restrict__ wprojT)
{
  const int bid = blockIdx.x, tid = threadIdx.x;
  __shared__ float tile[64][65];

  if (bid < 4096) {
    const int i = bid*256 + tid;
    const float4 v0 = ((const float4*)x)[2*i];
    const float4 v1 = ((const float4*)x)[2*i + 1];
    union { bf16 b[8]; uint4 u; } cvt;
    cvt.b[0] = __float2bfloat16(v0.x);
    cvt.b[1] = __float2bfloat16(v0.y);
    cvt.b[2] = __float2bfloat16(v0.z);
    cvt.b[3] = __float2bfloat16(v0.w);
    cvt.b[4] = __float2bfloat16(v1.x);
    cvt.b[5] = __float2bfloat16(v1.y);
    cvt.b[6] = __float2bfloat16(v1.z);
    cvt.b[7] = __float2bfloat16(v1.w);
    ((uint4*)xb)[i] = cvt.u;
    return;
  }

  const float* in; bf16* out; int N, n0, k0;
  if (bid < 4864) {
    const int j = bid - 4096;
    in = Wqkv; out = wqkvT; N = N3C;
    n0 = (j % 48) * 64; k0 = (j / 48) * 64;
  } else {
    const int j = bid - 4864;
    in = Wproj; out = wprojT; N = C_;
    n0 = (j % 16) * 64; k0 = (j / 16) * 64;
  }
  const int r = tid >> 6, c = tid & 63;
  #pragma unroll
  for (int j = 0; j < 16; ++j)
    tile[r + j*4][c] = in[(size_t)(k0 + r + j*4) * N + n0 + c];
  __syncthreads();
  #pragma unroll
  for (int j = 0; j < 16; ++j) {
    int rr = r + j*4;
    out[(size_t)(n0 + rr) * C_ + k0 + c] = __float2bfloat16(tile[c][rr]);
  }
}

// ---------------- GEMM: 128x128 tile, BK=32, 4-deep counted-vmcnt pipeline --
// R12: keep the proven 128^2 geometry (1536/512 blocks = exact grid rounds,
// 2 blocks/CU) but remove the barrier drain:
//  - BK=32 -> 8KB/operand/tile -> FOUR buffers in 64KB LDS.
//  - per iter: vmcnt(8) [tile i retired block-wide, i+1/i+2 in flight] ->
//    raw s_barrier -> stage tile i+3 (4 gld16) -> compute tile i
//    (8 ds_read_b128 + 16 MFMA/wave; one 16x16x32 MFMA spans K=32).
//  - WAR: stage(i+3) overwrites buf[(i-1)&3]; its readers' lgkm waits
//    precede their MFMAs which precede this barrier. RAW: every wave did
//    vmcnt(8) before the barrier. Distance-4 buffers never collide.
//  - 64B LDS rows: chunk c of row r at physical c^((r>>1)&3); bank-quad =
//    4*(r&1) + (c^swz) -> 16 lanes cover all 8 quads 2x = conflict-free.
//    Staging stays lane-linear (gld16-compatible) via pre-swizzled global
//    chunk gc = (t&3)^((row>>1)&3).
//  - k-accumulation order identical to R1 kernel -> identical numerics.
// MODE 0 epilogue: Q/K scatter (nb<16); V blocks (nb>=16) transpose via LDS
// to key-permuted Vt [B,H,HS,T]. MODE 1: fp32 + bias.
template<int MODE, int NB>
__global__ __launch_bounds__(256, 2)
void k_gemm(const bf16* __restrict__ A, const bf16* __restrict__ Bt,
            int N, int K,
            bf16* __restrict__ Qb, bf16* __restrict__ Kb, bf16* __restrict__ Vt,
            float* __restrict__ Out, const float* __restrict__ bias)
{
  __shared__ __align__(16) char smem[65536];
  bf16* const sA = (bf16*)smem;               // [4][4096]  128 rows x 32
  bf16* const sB = (bf16*)(smem + 32768);     // [4][4096]

  const int tid  = threadIdx.x;
  const int lane = tid & 63, wave = tid >> 6;
  const int quad = lane >> 4, l16 = lane & 15;
  const int wm = wave >> 1, wn = wave & 1;

  const int g = blockIdx.x;
  const int xcd = g & 7;
  const int local = g >> 3;
  const int nb = local % NB;
  const int mb = (local / NB) * 8 + xcd;
  const int m0 = mb * 128, n0 = nb * 128;

  // staging: thread t -> rows t>>2 and 64+(t>>2); phys chunk t&3 holds
  // global chunk (t&3)^((row>>1)&3) (row+64 keeps the same swizzle).
  const int ra = tid >> 2;
  const int gc = (tid & 3) ^ ((ra >> 1) & 3);
  const bf16* aptr = A  + (size_t)(m0 + ra) * K + gc*8;
  const bf16* bptr = Bt + (size_t)(n0 + ra) * K + gc*8;
  const size_t rj = (size_t)64 * K;

  const int KT = K >> 5;                      // 32 K-tiles
  floatx4 acc[4][4] = {};
  const int swz = (l16 >> 1) & 3;
  const int aoff = (wm*64 + l16)*32 + (quad ^ swz)*8;
  const int boff = (wn*64 + l16)*32 + (quad ^ swz)*8;

  // prologue: stage tiles 0..2 (12 loads in flight)
  #pragma unroll
  for (int t = 0; t < 3; ++t) {
    bf16* sa = sA + t*4096; bf16* sb = sB + t*4096;
    gld16(aptr + t*32,      sa + tid*8);
    gld16(aptr + rj + t*32, sa + 2048 + tid*8);
    gld16(bptr + t*32,      sb + tid*8);
    gld16(bptr + rj + t*32, sb + 2048 + tid*8);
  }

  #pragma unroll 1
  for (int i = 0; i < KT; ++i) {
    if (i < KT-2)       asm volatile("s_waitcnt vmcnt(8)" ::: "memory");
    else if (i == KT-2) asm volatile("s_waitcnt vmcnt(4)" ::: "memory");
    else                asm volatile("s_waitcnt vmcnt(0)" ::: "memory");
    asm volatile("s_barrier" ::: "memory");
    if (i < KT-3) {
      const int t = i + 3;
      bf16* sa = sA + (t & 3)*4096; bf16* sb = sB + (t & 3)*4096;
      gld16(aptr + t*32,      sa + tid*8);
      gld16(aptr + rj + t*32, sa + 2048 + tid*8);
      gld16(bptr + t*32,      sb + tid*8);
      gld16(bptr + rj + t*32, sb + 2048 + tid*8);
    }
    const bf16* sa = sA + (i & 3)*4096;
    const bf16* sb = sB + (i & 3)*4096;
    short8 af[4], bfm[4];
    #pragma unroll
    for (int ii = 0; ii < 4; ++ii) af[ii]  = *(const short8*)&sa[aoff + ii*512];
    #pragma unroll
    for (int j = 0; j < 4; ++j)    bfm[j]  = *(const short8*)&sb[boff + j*512];
    __builtin_amdgcn_s_setprio(1);
    #pragma unroll
    for (int ii = 0; ii < 4; ++ii)
      #pragma unroll
      for (int j = 0; j < 4; ++j)
        acc[ii][j] = MFMA16(af[ii], bfm[j], acc[ii][j]);
    __builtin_amdgcn_s_setprio(0);
  }

  if (MODE == 0 && nb >= 16) {
    // ---- V block: LDS transpose -> coalesced, key-permuted Vt stores ----
    __syncthreads();                      // all waves done with sA/sB
    unsigned short* epi = (unsigned short*)smem;   // [128 cc][132 pad]
    #pragma unroll
    for (int i = 0; i < 4; ++i) {
      const int tl = wm*64 + i*16 + quad*4;
      #pragma unroll
      for (int j = 0; j < 4; ++j) {
        const int ccl = wn*64 + j*16 + l16;
        #pragma unroll
        for (int r = 0; r < 4; ++r)
          epi[ccl*132 + tl + r] = f2bf_us(acc[i][j][r]);
      }
    }
    __syncthreads();
    const int b  = m0 >> 11;
    const int t0 = m0 & 2047;            // token offset within this sequence
    const int h0 = (n0 - 2*C_) >> 6;
    #pragma unroll
    for (int it = 0; it < 32; ++it) {
      const int id = it*256 + tid;
      const int tp = id & 31;
      const int rest = id >> 5;
      const int tl64 = (rest & 1) * 64;
      const int ccl = rest >> 1;
      const int k0p = tp + (tp & 16);     // keys (k0p, k0p+16) -> positions (2tp, 2tp+1)
      const unsigned lo = epi[ccl*132 + tl64 + k0p];
      const unsigned hi = epi[ccl*132 + tl64 + k0p + 16];
      const int h = h0 + (ccl >> 6), d = ccl & 63;
      unsigned* row = (unsigned*)(Vt + ((size_t)(b*H_ + h) * HS_ + d) * T_);
      row[(t0 >> 1) + tl64/2 + tp] = lo | (hi << 16);
    }
  } else {
    #pragma unroll
    for (int i = 0; i < 4; ++i) {
      const int rowb = m0 + wm*64 + i*16 + quad*4;
      #pragma unroll
      for (int j = 0; j < 4; ++j) {
        const int col = n0 + wn*64 + j*16 + l16;
        #pragma unroll
        for (int r = 0; r < 4; ++r) {
          const float v = acc[i][j][r];
          const int rr = rowb + r;
          if (MODE == 0) {
            const int b = rr >> 11, t = rr & 2047;
            const int h = (col >> 6) & 15, d = col & 63;
            const size_t addr = (((size_t)(b*H_ + h) * T_ + t) << 6) + d;
            if (nb < 8) {
              // fold 1/sqrt(64) * log2(e) so attention softmax can use exp2
              Qb[addr] = __float2bfloat16(v * 0.18033688f);
            } else {
              Kb[addr] = __float2bfloat16(v);
            }
          } else {
            Out[(size_t)rr * N + col] = v + bias[col];
          }
        }
      }
    }
  }
}

// ---------------- flash attention (causal) ----------------------------------
__global__ __launch_bounds__(256, 3)
void k_attn(const bf16* __restrict__ Q, const bf16* __restrict__ K,
            const bf16* __restrict__ Vt, bf16* __restrict__ att)
{
  __shared__ bf16 kbuf[2][64*64];   // [buf][key][dc^key&7]
  __shared__ bf16 vbuf[2][64*64];   // [buf][d][pc^d&7]  (positions, permuted)
  __shared__ bf16 pbuf[4][32*64];   // per-wave [q][(pc+q)&7 rotation]

  const int tid  = threadIdx.x;
  const int lane = tid & 63, wave = tid >> 6;
  const int quad = lane >> 4, l16 = lane & 15;
  const int x7 = l16 & 7;

  const int g  = blockIdx.x;              // 1024 blocks
  const int bh = (g & 7) * 8 + ((g >> 3) & 7);  // 16 blocks of a bh share XCD g&7
  const int qt = 15 - (g >> 6);           // q-tile index; heavy (qt=15) first
  const int b = bh >> 4, h = bh & 15;

  const bf16* Qp = Q  + (size_t)bh * T_ * HS_;
  const bf16* Kp = K  + (size_t)bh * T_ * HS_;
  const bf16* Vp = Vt + (size_t)bh * HS_ * T_;

  const int qbase = qt*128 + wave*32;
  const int ntk = 2*qt + 2;               // key tiles to process

  short8 qf[2][2];
  #pragma unroll
  for (int mt = 0; mt < 2; ++mt)
    #pragma unroll
    for (int ss = 0; ss < 2; ++ss)
      qf[mt][ss] = *(const short8*)(Qp + (size_t)(qbase + mt*16 + l16) * HS_ + ss*32 + quad*8);

  floatx4 o[2][4] = {};
  float lrow[2][4] = {};

  const bf16* kg[2]; const bf16* vg[2];
  int ldsoff[2];
  #pragma unroll
  for (int it = 0; it < 2; ++it) {
    const int c = it*256 + tid;
    const int row = c >> 3;
    const int col = (c & 7) ^ (row & 7);
    kg[it] = Kp + (size_t)row * HS_ + col*8;
    vg[it] = Vp + (size_t)row * T_ + col*8;
    ldsoff[it] = c*8;
  }

  bf16* pw = pbuf[wave];
  unsigned int* pw32 = (unsigned int*)pw;
  const int c0 = l16 >> 2;
  const int dwl = l16 & 3;

  for (int i = 0; i <= ntk; ++i) {
    __syncthreads();
    if (i < ntk) {
      const int stk0 = i * 64;
      bf16* kb = kbuf[i & 1];
      bf16* vb = vbuf[i & 1];
      #pragma unroll
      for (int it = 0; it < 2; ++it) {
        gld16(kg[it] + (size_t)stk0 * HS_, kb + ldsoff[it]);
        gld16(vg[it] + stk0,               vb + ldsoff[it]);
      }
    }
    if (i == 0) continue;
    const int tk  = i - 1;
    const int tk0 = tk * 64;
    if (tk0 > qbase + 31) continue;
    const bf16* kb = kbuf[tk & 1];
    const bf16* vb = vbuf[tk & 1];

    floatx4 s[2][4] = {};
    __builtin_amdgcn_s_setprio(1);
    #pragma unroll
    for (int nt = 0; nt < 4; ++nt) {
      const int key = nt*16 + l16;
      #pragma unroll
      for (int ss = 0; ss < 2; ++ss) {
        short8 kf = *(const short8*)&kb[(key*8 + ((ss*4+quad) ^ x7))*8];
        s[0][nt] = MFMA16(qf[0][ss], kf, s[0][nt]);
        s[1][nt] = MFMA16(qf[1][ss], kf, s[1][nt]);
      }
    }
    __builtin_amdgcn_s_setprio(0);

    if (tk0 + 63 > qbase) {
      #pragma unroll
      for (int mt = 0; mt < 2; ++mt)
        #pragma unroll
        for (int nt = 0; nt < 4; ++nt) {
          const int key = tk0 + nt*16 + l16;
          #pragma unroll
          for (int r = 0; r < 4; ++r) {
            const int qr = qbase + mt*16 + quad*4 + r;
            if (key > qr) s[mt][nt][r] = -1e30f;
          }
        }
    }

    #pragma unroll
    for (int mt = 0; mt < 2; ++mt) {
      #pragma unroll
      for (int r = 0; r < 4; ++r) {
        const float p0 = EXP2(s[mt][0][r]), p1 = EXP2(s[mt][1][r]);
        const float p2 = EXP2(s[mt][2][r]), p3 = EXP2(s[mt][3][r]);
        lrow[mt][r] += (p0 + p1) + (p2 + p3);
        const int q = mt*16 + quad*4 + r;
        const unsigned w0 = __builtin_amdgcn_perm(__float_as_uint(p1), __float_as_uint(p0), 0x07060302u);
        const unsigned w1 = __builtin_amdgcn_perm(__float_as_uint(p3), __float_as_uint(p2), 0x07060302u);
        pw32[q*32 + (((c0 + q)     & 7) << 2) + dwl] = w0;
        pw32[q*32 + (((c0 + q + 4) & 7) << 2) + dwl] = w1;
      }
    }

    __builtin_amdgcn_s_setprio(1);
    #pragma unroll
    for (int ss = 0; ss < 2; ++ss) {
      short8 pf0 = *(const short8*)&pw[l16*64      + ((4*ss + quad + l16) & 7)*8];
      short8 pf1 = *(const short8*)&pw[(16+l16)*64 + ((4*ss + quad + l16) & 7)*8];
      #pragma unroll
      for (int nd = 0; nd < 4; ++nd) {
        const int d = nd*16 + l16;
        short8 vf = *(const short8*)&vb[(d*8 + ((ss*4+quad) ^ x7))*8];
        o[0][nd] = MFMA16(pf0, vf, o[0][nd]);
        o[1][nd] = MFMA16(pf1, vf, o[1][nd]);
      }
    }
    __builtin_amdgcn_s_setprio(0);
  }

  #pragma unroll
  for (int mt = 0; mt < 2; ++mt) {
    #pragma unroll
    for (int r = 0; r < 4; ++r) {
      float lsum = lrow[mt][r];
      lsum += __shfl_xor(lsum, 1);
      lsum += __shfl_xor(lsum, 2);
      lsum += __shfl_xor(lsum, 4);
      lsum += __shfl_xor(lsum, 8);
      const float inv = 1.0f / lsum;
      const int tt = qbase + mt*16 + quad*4 + r;
      #pragma unroll
      for (int nd = 0; nd < 4; ++nd)
        att[(size_t)(b*T_ + tt) * C_ + h*64 + nd*16 + l16] =
            __float2bfloat16(o[mt][nd][r] * inv);
    }
  }
}

extern "C" void kernel_launch(void* const* d_in, const int* in_sizes, int n_in,
                              void* d_out, int out_size, void* d_ws, size_t ws_size,
                              hipStream_t stream) {
  const float* x     = (const float*)d_in[0];
  const float* Wqkv  = (const float*)d_in[1];
  const float* Wproj = (const float*)d_in[2];
  const float* bproj = (const float*)d_in[3];
  float* out = (float*)d_out;

  char* ws = (char*)d_ws;
  bf16* xb     = (bf16*)(ws + 0);          // 8192x1024       16,777,216 B
  bf16* wqkvT  = (bf16*)(ws + 16777216);   // 3072x1024        6,291,456 B
  bf16* wprojT = (bf16*)(ws + 23068672);   // 1024x1024        2,097,152 B
  bf16* Qb     = (bf16*)(ws + 25165824);   // [B,H,T,HS]      16,777,216 B
  bf16* Kb     = (bf16*)(ws + 41943040);   // [B,H,T,HS]      16,777,216 B
  bf16* Vt     = (bf16*)(ws + 58720256);   // [B,H,HS,T] perm 16,777,216 B
  bf16* att    = (bf16*)(ws + 75497472);   // [B,T,C]         16,777,216 B

  k_prep<<<dim3(5120), 256, 0, stream>>>(x, xb, Wqkv, wqkvT, Wproj, wprojT);
  k_gemm<0, 24><<<dim3(1536), 256, 0, stream>>>(
      xb, wqkvT, N3C, C_, Qb, Kb, Vt, nullptr, nullptr);
  k_attn<<<dim3(1024), 256, 0, stream>>>(Qb, Kb, Vt, att);
  k_gemm<1, 8><<<dim3(512), 256, 0, stream>>>(
      att, wprojT, C_, C_, nullptr, nullptr, nullptr, out, bproj);
}